// Round 2
// baseline (426.808 us; speedup 1.0000x reference)
//
#include <hip/hip_runtime.h>
#include <hip/hip_cooperative_groups.h>

namespace cg = cooperative_groups;

// HeteroScorePredictor: 3 etypes of per-edge u·v gather-dot.
//   out[0:E)    = dot(h_user[src_clicks[e]],    h_item[dst_clicks[e]])
//   out[E:2E)   = dot(h_item[src_clickedby[e]], h_user[dst_clickedby[e]])
//   out[2E:3E)  = dot(h_user[src_follows[e]],   h_user[dst_follows[e]])
//
// R4: gather path pinned ~3.6 TB/s; int8 row == one 128B line is optimal.
// R5: nt hints on idx/out = neutral (FETCH 167.7->166.8 MB), reverted.
// R6 analysis: FETCH=167 MB is the per-XCD compulsory-miss FLOOR:
//   user: 8 XCDs x 100k(1-e^-2.5) rows x 128B = 94 MB
//   item: 8 XCDs x 100k(1-e^-1.25) rows x 128B = 73 MB  -> 167 MB = measured.
// Sorting/binning schemes all re-derive to >=167 MB. Score kernel is done.
// R6 change: fuse quantize+score into ONE cooperative kernel (grid-stride,
// occupancy-sized grid, grid.sync between phases) to remove the kernel
// boundary (launch gap + drain + L2 flush). Fallback to split kernels if
// cooperative launch is unavailable.

#define NEDGE 500000
#define DIM 128
#define N_USER 100000
#define N_ITEM 100000
#define NROWS (N_USER + N_ITEM)

typedef float f32x4 __attribute__((ext_vector_type(4)));

// ---------------- shared device bodies ----------------

// one quantize work-item: t in [0, NROWS*32); 32 lanes per 128-float row
__device__ __forceinline__ void quant_item(
    int t, const float* __restrict__ h_user, const float* __restrict__ h_item,
    signed char* __restrict__ qu, signed char* __restrict__ qi,
    float* __restrict__ su, float* __restrict__ sitem)
{
    const int row  = t >> 5;
    const int lane = t & 31;

    const float* src; signed char* dst; float* sc; int r;
    if (row < N_USER) { src = h_user; dst = qu; sc = su; r = row; }
    else              { src = h_item; dst = qi; sc = sitem; r = row - N_USER; }

    // read-once stream: non-temporal (keep L2 clean for the score phase)
    const f32x4 v = __builtin_nontemporal_load(
        reinterpret_cast<const f32x4*>(src + (size_t)r * DIM) + lane);

    float m = fmaxf(fmaxf(fabsf(v.x), fabsf(v.y)), fmaxf(fabsf(v.z), fabsf(v.w)));
    #pragma unroll
    for (int off = 16; off > 0; off >>= 1)
        m = fmaxf(m, __shfl_xor(m, off, 32));

    const float scale = m * (1.0f / 127.0f);
    const float inv   = (m > 0.f) ? 127.0f / m : 0.f;

    int q0 = (int)rintf(v.x * inv);
    int q1 = (int)rintf(v.y * inv);
    int q2 = (int)rintf(v.z * inv);
    int q3 = (int)rintf(v.w * inv);
    q0 = max(-127, min(127, q0));
    q1 = max(-127, min(127, q1));
    q2 = max(-127, min(127, q2));
    q3 = max(-127, min(127, q3));

    const unsigned int packed =
        ((unsigned)(q0 & 0xff)) | ((unsigned)(q1 & 0xff) << 8) |
        ((unsigned)(q2 & 0xff) << 16) | ((unsigned)(q3 & 0xff) << 24);
    reinterpret_cast<unsigned int*>(dst + (size_t)r * DIM)[lane] = packed;
    if (lane == 0) sc[r] = scale;
}

__device__ __forceinline__ int sdot4(int a, int b, int acc)
{
#if defined(__has_builtin) && __has_builtin(__builtin_amdgcn_sdot4)
    return __builtin_amdgcn_sdot4(a, b, acc, false);
#else
    #pragma unroll
    for (int k = 0; k < 32; k += 8) {
        const int av = (a << (24 - k)) >> 24;
        const int bv = (b << (24 - k)) >> 24;
        acc += av * bv;
    }
    return acc;
#endif
}

__device__ __forceinline__ int dot16_i8(uint4 a, uint4 b, int acc)
{
    acc = sdot4((int)a.x, (int)b.x, acc);
    acc = sdot4((int)a.y, (int)b.y, acc);
    acc = sdot4((int)a.z, (int)b.z, acc);
    acc = sdot4((int)a.w, (int)b.w, acc);
    return acc;
}

__device__ __forceinline__ void resolve_edge_i8(
    int f,
    const signed char* qu, const signed char* qi,
    const float* su, const float* sitem,
    const int* sc, const int* dc, const int* scb, const int* dcb,
    const int* sf, const int* df,
    const signed char*& hs, const signed char*& hd,
    const float*& ss, const float*& sd,
    const int*& si, const int*& di, int& e)
{
    if (f < NEDGE) {
        e = f;             si = sc;  di = dc;  hs = qu; hd = qi; ss = su;    sd = sitem;
    } else if (f < 2 * NEDGE) {
        e = f - NEDGE;     si = scb; di = dcb; hs = qi; hd = qu; ss = sitem; sd = su;
    } else {
        e = f - 2 * NEDGE; si = sf;  di = df;  hs = qu; hd = qu; ss = su;    sd = su;
    }
}

// one score group: 8 lanes, 2 edges (f0=2g, f1=2g+1; 3*NEDGE is even)
__device__ __forceinline__ void score_pair(
    int g, int lane,
    const signed char* __restrict__ qu, const signed char* __restrict__ qi,
    const float* __restrict__ su, const float* __restrict__ sitem,
    const int* __restrict__ sc,  const int* __restrict__ dc,
    const int* __restrict__ scb, const int* __restrict__ dcb,
    const int* __restrict__ sf,  const int* __restrict__ df,
    float* __restrict__ out)
{
    const int f0 = 2 * g;
    const int f1 = f0 + 1;

    const signed char *hs0, *hd0, *hs1, *hd1;
    const float *ss0, *sd0, *ss1, *sd1;
    const int *si0, *di0, *si1, *di1;
    int e0, e1;
    resolve_edge_i8(f0, qu, qi, su, sitem, sc, dc, scb, dcb, sf, df,
                    hs0, hd0, ss0, sd0, si0, di0, e0);
    resolve_edge_i8(f1, qu, qi, su, sitem, sc, dc, scb, dcb, sf, df,
                    hs1, hd1, ss1, sd1, si1, di1, e1);

    const int s0 = si0[e0];
    const int d0 = di0[e0];
    const int s1 = si1[e1];
    const int d1 = di1[e1];

    // scale loads early (tiny arrays, L2-resident, heavy reuse)
    const float sca0 = ss0[s0] * sd0[d0];
    const float sca1 = ss1[s1] * sd1[d1];

    // 8 lanes x 16 B = 128 B = one int8 row; 4 independent gathers in flight
    const uint4 a0 = reinterpret_cast<const uint4*>(hs0 + (size_t)s0 * DIM)[lane];
    const uint4 b0 = reinterpret_cast<const uint4*>(hd0 + (size_t)d0 * DIM)[lane];
    const uint4 a1 = reinterpret_cast<const uint4*>(hs1 + (size_t)s1 * DIM)[lane];
    const uint4 b1 = reinterpret_cast<const uint4*>(hd1 + (size_t)d1 * DIM)[lane];

    int i0 = dot16_i8(a0, b0, 0);
    int i1 = dot16_i8(a1, b1, 0);

    #pragma unroll
    for (int off = 4; off > 0; off >>= 1) {
        i0 += __shfl_down(i0, off, 8);
        i1 += __shfl_down(i1, off, 8);
    }

    if (lane == 0) {
        out[f0] = (float)i0 * sca0;
        out[f1] = (float)i1 * sca1;
    }
}

// ---------------- fused cooperative kernel (persistent grid) ----------------
__global__ __launch_bounds__(256) void fused_coop(
    const float* __restrict__ h_user, const float* __restrict__ h_item,
    signed char* __restrict__ qu, signed char* __restrict__ qi,
    float* __restrict__ su, float* __restrict__ sitem,
    const int* __restrict__ sc,  const int* __restrict__ dc,
    const int* __restrict__ scb, const int* __restrict__ dcb,
    const int* __restrict__ sf,  const int* __restrict__ df,
    float* __restrict__ out)
{
    const int nthreads = gridDim.x * blockDim.x;   // multiple of 256
    const int tid = blockIdx.x * blockDim.x + threadIdx.x;

    // phase 1: quantize both tables (grid-stride; stride keeps 32-lane rows
    // wave-aligned since nthreads % 64 == 0)
    for (int t = tid; t < NROWS * 32; t += nthreads)
        quant_item(t, h_user, h_item, qu, qi, su, sitem);

    __threadfence();           // device-scope: publish int8 tables across XCDs
    cg::this_grid().sync();

    // phase 2: score (grid-stride over 8-lane groups, 2 edges each)
    const int lane    = threadIdx.x & 7;
    const int ngroups = (3 * NEDGE) / 2;
    const int gstep   = nthreads >> 3;
    for (int g = tid >> 3; g < ngroups; g += gstep)
        score_pair(g, lane, qu, qi, su, sitem, sc, dc, scb, dcb, sf, df, out);
}

// ---------------- split kernels (fallback path) ----------------
__global__ __launch_bounds__(256) void quantize_rows(
    const float* __restrict__ h_user, const float* __restrict__ h_item,
    signed char* __restrict__ qu, signed char* __restrict__ qi,
    float* __restrict__ su, float* __restrict__ sitem)
{
    const int tid = blockIdx.x * blockDim.x + threadIdx.x;
    if (tid >= NROWS * 32) return;
    quant_item(tid, h_user, h_item, qu, qi, su, sitem);
}

__global__ __launch_bounds__(256) void hetero_score_i8(
    const signed char* __restrict__ qu, const signed char* __restrict__ qi,
    const float* __restrict__ su, const float* __restrict__ sitem,
    const int* __restrict__ sc,  const int* __restrict__ dc,
    const int* __restrict__ scb, const int* __restrict__ dcb,
    const int* __restrict__ sf,  const int* __restrict__ df,
    float* __restrict__ out)
{
    const int tid  = blockIdx.x * blockDim.x + threadIdx.x;
    const int g    = tid >> 3;
    const int lane = tid & 7;
    if (2 * g >= 3 * NEDGE) return;
    score_pair(g, lane, qu, qi, su, sitem, sc, dc, scb, dcb, sf, df, out);
}

// ---------------- fp32 fallback if ws too small ----------------
__global__ __launch_bounds__(256) void hetero_score_f32(
    const float* __restrict__ hu,
    const float* __restrict__ hi,
    const int* __restrict__ sc,  const int* __restrict__ dc,
    const int* __restrict__ scb, const int* __restrict__ dcb,
    const int* __restrict__ sf,  const int* __restrict__ df,
    float* __restrict__ out)
{
    const int tid  = blockIdx.x * blockDim.x + threadIdx.x;
    const int g    = tid >> 5;
    const int lane = tid & 31;
    if (g >= 3 * NEDGE) return;

    const float *hs, *hd;
    const int *si, *di;
    int e;
    if (g < NEDGE) {
        e = g;             si = sc;  di = dc;  hs = hu; hd = hi;
    } else if (g < 2 * NEDGE) {
        e = g - NEDGE;     si = scb; di = dcb; hs = hi; hd = hu;
    } else {
        e = g - 2 * NEDGE; si = sf;  di = df;  hs = hu; hd = hu;
    }

    const int s = si[e];
    const int d = di[e];
    const float4 a = *reinterpret_cast<const float4*>(hs + (size_t)s * DIM + lane * 4);
    const float4 b = *reinterpret_cast<const float4*>(hd + (size_t)d * DIM + lane * 4);
    float sum = a.x * b.x + a.y * b.y + a.z * b.z + a.w * b.w;
    #pragma unroll
    for (int off = 16; off > 0; off >>= 1)
        sum += __shfl_down(sum, off, 32);
    if (lane == 0) out[g] = sum;
}

extern "C" void kernel_launch(void* const* d_in, const int* in_sizes, int n_in,
                              void* d_out, int out_size, void* d_ws, size_t ws_size,
                              hipStream_t stream) {
    const float* h_user        = (const float*)d_in[0];
    const float* h_item        = (const float*)d_in[1];
    const int*   src_clicks    = (const int*)d_in[2];
    const int*   dst_clicks    = (const int*)d_in[3];
    const int*   src_clickedby = (const int*)d_in[4];
    const int*   dst_clickedby = (const int*)d_in[5];
    const int*   src_follows   = (const int*)d_in[6];
    const int*   dst_follows   = (const int*)d_in[7];
    float* out = (float*)d_out;

    const size_t user_bytes = (size_t)N_USER * DIM;           // 12.8 MB int8
    const size_t item_bytes = (size_t)N_ITEM * DIM;           // 12.8 MB int8
    const size_t need = user_bytes + item_bytes
                      + (size_t)(N_USER + N_ITEM) * sizeof(float);

    if (ws_size >= need) {
        signed char* qu = (signed char*)d_ws;
        signed char* qi = qu + user_bytes;
        float* su    = (float*)(qi + item_bytes);
        float* sitem = su + N_USER;

        // try the fused cooperative path: occupancy-sized persistent grid
        bool coop_done = false;
        int maxb = 0;
        if (hipOccupancyMaxActiveBlocksPerMultiprocessor(&maxb, fused_coop, 256, 0)
                == hipSuccess && maxb > 0) {
            long long grid = (long long)maxb * 256;   // 256 CUs on MI355X
            if (grid > 4096) grid = 4096;
            void* args[] = {
                (void*)&h_user, (void*)&h_item, (void*)&qu, (void*)&qi,
                (void*)&su, (void*)&sitem,
                (void*)&src_clicks, (void*)&dst_clicks,
                (void*)&src_clickedby, (void*)&dst_clickedby,
                (void*)&src_follows, (void*)&dst_follows, (void*)&out };
            hipError_t le = hipLaunchCooperativeKernel(
                (void*)fused_coop, dim3((unsigned)grid), dim3(256), args, 0, stream);
            if (le == hipSuccess) coop_done = true;
            else (void)hipGetLastError();             // clear, fall back
        }

        if (!coop_done) {
            const long long qthreads = (long long)NROWS * 32;
            quantize_rows<<<(int)((qthreads + 255) / 256), 256, 0, stream>>>(
                h_user, h_item, qu, qi, su, sitem);

            const long long n_groups = (3LL * NEDGE) / 2;
            const long long sthreads = n_groups * 8;
            hetero_score_i8<<<(int)((sthreads + 255) / 256), 256, 0, stream>>>(
                qu, qi, su, sitem, src_clicks, dst_clicks, src_clickedby,
                dst_clickedby, src_follows, dst_follows, out);
        }
    } else {
        const long long total_threads = 3LL * NEDGE * 32;
        hetero_score_f32<<<(int)((total_threads + 255) / 256), 256, 0, stream>>>(
            h_user, h_item, src_clicks, dst_clicks, src_clickedby, dst_clickedby,
            src_follows, dst_follows, out);
    }
}

// Round 3
// 186.540 us; speedup vs baseline: 2.2880x; 2.2880x over previous
//
#include <hip/hip_runtime.h>

// HeteroScorePredictor: 3 etypes of per-edge u·v gather-dot.
//   out[0:E)    = dot(h_user[src_clicks[e]],    h_item[dst_clicks[e]])
//   out[E:2E)   = dot(h_item[src_clickedby[e]], h_user[dst_clickedby[e]])
//   out[2E:3E)  = dot(h_user[src_follows[e]],   h_user[dst_follows[e]])
//
// R4: gather path pinned ~3.6 TB/s; int8 row == one 128B line is optimal.
// R5: nt hints on score idx/out = neutral (FETCH 167.7->166.8MB), reverted.
// R6: cooperative persistent-grid fusion = 4.5x REGRESSION (440us, HBM
//     589GB/s, VALU 6%): grid-stride serializes gathers per thread; the
//     retire-and-replace block scheduler IS the MLP engine. Never again.
// R7 (this round): split kernels restored. Score kernel is at its
//     per-XCD compulsory-miss floor (user 94MB + item 73MB = 167MB =
//     measured FETCH) — untouched. Quantize tightened toward its ~21us
//     stream floor: 16 lanes/row, 2 independent float4 loads/lane (2x
//     per-thread MLP), 4-step reduce, half the threads. Same math ->
//     bit-identical output.

#define NEDGE 500000
#define DIM 128
#define N_USER 100000
#define N_ITEM 100000
#define NROWS (N_USER + N_ITEM)

typedef float f32x4 __attribute__((ext_vector_type(4)));

// ---------------- per-row int8 quantization: 16 lanes per 128-float row ----
__global__ __launch_bounds__(256) void quantize_rows(
    const float* __restrict__ h_user, const float* __restrict__ h_item,
    signed char* __restrict__ qu, signed char* __restrict__ qi,
    float* __restrict__ su, float* __restrict__ sitem)
{
    const int tid  = blockIdx.x * blockDim.x + threadIdx.x;
    const int row  = tid >> 4;          // 16 lanes per row
    const int lane = tid & 15;
    if (row >= NROWS) return;

    const float* src; signed char* dst; float* sc; int r;
    if (row < N_USER) { src = h_user; dst = qu; sc = su; r = row; }
    else              { src = h_item; dst = qi; sc = sitem; r = row - N_USER; }

    // read-once fp32 stream: non-temporal; two independent 16B loads in flight
    const f32x4* rp = reinterpret_cast<const f32x4*>(src + (size_t)r * DIM);
    const f32x4 v0 = __builtin_nontemporal_load(rp + lane);
    const f32x4 v1 = __builtin_nontemporal_load(rp + lane + 16);

    float m = fmaxf(fmaxf(fabsf(v0.x), fabsf(v0.y)), fmaxf(fabsf(v0.z), fabsf(v0.w)));
    m = fmaxf(m, fmaxf(fmaxf(fabsf(v1.x), fabsf(v1.y)), fmaxf(fabsf(v1.z), fabsf(v1.w))));
    #pragma unroll
    for (int off = 8; off > 0; off >>= 1)
        m = fmaxf(m, __shfl_xor(m, off, 16));

    const float scale = m * (1.0f / 127.0f);
    const float inv   = (m > 0.f) ? 127.0f / m : 0.f;

    int q0 = (int)rintf(v0.x * inv), q1 = (int)rintf(v0.y * inv);
    int q2 = (int)rintf(v0.z * inv), q3 = (int)rintf(v0.w * inv);
    int q4 = (int)rintf(v1.x * inv), q5 = (int)rintf(v1.y * inv);
    int q6 = (int)rintf(v1.z * inv), q7 = (int)rintf(v1.w * inv);
    q0 = max(-127, min(127, q0)); q1 = max(-127, min(127, q1));
    q2 = max(-127, min(127, q2)); q3 = max(-127, min(127, q3));
    q4 = max(-127, min(127, q4)); q5 = max(-127, min(127, q5));
    q6 = max(-127, min(127, q6)); q7 = max(-127, min(127, q7));

    const unsigned int w0 =
        ((unsigned)(q0 & 0xff)) | ((unsigned)(q1 & 0xff) << 8) |
        ((unsigned)(q2 & 0xff) << 16) | ((unsigned)(q3 & 0xff) << 24);
    const unsigned int w1 =
        ((unsigned)(q4 & 0xff)) | ((unsigned)(q5 & 0xff) << 8) |
        ((unsigned)(q6 & 0xff) << 16) | ((unsigned)(q7 & 0xff) << 24);

    // int8 tables + scales are re-read by the score kernel: normal cached stores
    unsigned int* wp = reinterpret_cast<unsigned int*>(dst + (size_t)r * DIM);
    wp[lane]      = w0;   // floats [4*lane .. 4*lane+3]
    wp[lane + 16] = w1;   // floats [4*(lane+16) .. ]
    if (lane == 0) sc[r] = scale;
}

// ---------------- int8 dot helpers ----------------
__device__ __forceinline__ int sdot4(int a, int b, int acc)
{
#if defined(__has_builtin) && __has_builtin(__builtin_amdgcn_sdot4)
    return __builtin_amdgcn_sdot4(a, b, acc, false);
#else
    #pragma unroll
    for (int k = 0; k < 32; k += 8) {
        const int av = (a << (24 - k)) >> 24;
        const int bv = (b << (24 - k)) >> 24;
        acc += av * bv;
    }
    return acc;
#endif
}

__device__ __forceinline__ int dot16_i8(uint4 a, uint4 b, int acc)
{
    acc = sdot4((int)a.x, (int)b.x, acc);
    acc = sdot4((int)a.y, (int)b.y, acc);
    acc = sdot4((int)a.z, (int)b.z, acc);
    acc = sdot4((int)a.w, (int)b.w, acc);
    return acc;
}

// ---------------- int8 gather-dot: 8-lane group, 2 edges unrolled ----------
__device__ __forceinline__ void resolve_edge_i8(
    int f,
    const signed char* qu, const signed char* qi,
    const float* su, const float* sitem,
    const int* sc, const int* dc, const int* scb, const int* dcb,
    const int* sf, const int* df,
    const signed char*& hs, const signed char*& hd,
    const float*& ss, const float*& sd,
    const int*& si, const int*& di, int& e)
{
    if (f < NEDGE) {
        e = f;             si = sc;  di = dc;  hs = qu; hd = qi; ss = su;    sd = sitem;
    } else if (f < 2 * NEDGE) {
        e = f - NEDGE;     si = scb; di = dcb; hs = qi; hd = qu; ss = sitem; sd = su;
    } else {
        e = f - 2 * NEDGE; si = sf;  di = df;  hs = qu; hd = qu; ss = su;    sd = su;
    }
}

__global__ __launch_bounds__(256) void hetero_score_i8(
    const signed char* __restrict__ qu, const signed char* __restrict__ qi,
    const float* __restrict__ su, const float* __restrict__ sitem,
    const int* __restrict__ sc,  const int* __restrict__ dc,
    const int* __restrict__ scb, const int* __restrict__ dcb,
    const int* __restrict__ sf,  const int* __restrict__ df,
    float* __restrict__ out)
{
    const int tid  = blockIdx.x * blockDim.x + threadIdx.x;
    const int g    = tid >> 3;        // 8-lane group; 2 edges per group
    const int lane = tid & 7;

    const int f0 = 2 * g;
    const int f1 = f0 + 1;
    if (f0 >= 3 * NEDGE) return;      // 3*NEDGE even -> f1 valid when f0 is

    const signed char *hs0, *hd0, *hs1, *hd1;
    const float *ss0, *sd0, *ss1, *sd1;
    const int *si0, *di0, *si1, *di1;
    int e0, e1;
    resolve_edge_i8(f0, qu, qi, su, sitem, sc, dc, scb, dcb, sf, df,
                    hs0, hd0, ss0, sd0, si0, di0, e0);
    resolve_edge_i8(f1, qu, qi, su, sitem, sc, dc, scb, dcb, sf, df,
                    hs1, hd1, ss1, sd1, si1, di1, e1);

    const int s0 = si0[e0];
    const int d0 = di0[e0];
    const int s1 = si1[e1];
    const int d1 = di1[e1];

    // scale loads early (tiny arrays, L2-resident) to overlap with gathers
    const float sca0 = ss0[s0] * sd0[d0];
    const float sca1 = ss1[s1] * sd1[d1];

    // 8 lanes x 16 B = 128 B = one int8 row; 4 independent gathers in flight
    const uint4 a0 = reinterpret_cast<const uint4*>(hs0 + (size_t)s0 * DIM)[lane];
    const uint4 b0 = reinterpret_cast<const uint4*>(hd0 + (size_t)d0 * DIM)[lane];
    const uint4 a1 = reinterpret_cast<const uint4*>(hs1 + (size_t)s1 * DIM)[lane];
    const uint4 b1 = reinterpret_cast<const uint4*>(hd1 + (size_t)d1 * DIM)[lane];

    int i0 = dot16_i8(a0, b0, 0);
    int i1 = dot16_i8(a1, b1, 0);

    #pragma unroll
    for (int off = 4; off > 0; off >>= 1) {
        i0 += __shfl_down(i0, off, 8);
        i1 += __shfl_down(i1, off, 8);
    }

    if (lane == 0) {
        out[f0] = (float)i0 * sca0;
        out[f1] = (float)i1 * sca1;
    }
}

// ---------------- fp32 fallback if ws too small ----------------
__global__ __launch_bounds__(256) void hetero_score_f32(
    const float* __restrict__ hu,
    const float* __restrict__ hi,
    const int* __restrict__ sc,  const int* __restrict__ dc,
    const int* __restrict__ scb, const int* __restrict__ dcb,
    const int* __restrict__ sf,  const int* __restrict__ df,
    float* __restrict__ out)
{
    const int tid  = blockIdx.x * blockDim.x + threadIdx.x;
    const int g    = tid >> 5;
    const int lane = tid & 31;
    if (g >= 3 * NEDGE) return;

    const float *hs, *hd;
    const int *si, *di;
    int e;
    if (g < NEDGE) {
        e = g;             si = sc;  di = dc;  hs = hu; hd = hi;
    } else if (g < 2 * NEDGE) {
        e = g - NEDGE;     si = scb; di = dcb; hs = hi; hd = hu;
    } else {
        e = g - 2 * NEDGE; si = sf;  di = df;  hs = hu; hd = hu;
    }

    const int s = si[e];
    const int d = di[e];
    const float4 a = *reinterpret_cast<const float4*>(hs + (size_t)s * DIM + lane * 4);
    const float4 b = *reinterpret_cast<const float4*>(hd + (size_t)d * DIM + lane * 4);
    float sum = a.x * b.x + a.y * b.y + a.z * b.z + a.w * b.w;
    #pragma unroll
    for (int off = 16; off > 0; off >>= 1)
        sum += __shfl_down(sum, off, 32);
    if (lane == 0) out[g] = sum;
}

extern "C" void kernel_launch(void* const* d_in, const int* in_sizes, int n_in,
                              void* d_out, int out_size, void* d_ws, size_t ws_size,
                              hipStream_t stream) {
    const float* h_user        = (const float*)d_in[0];
    const float* h_item        = (const float*)d_in[1];
    const int*   src_clicks    = (const int*)d_in[2];
    const int*   dst_clicks    = (const int*)d_in[3];
    const int*   src_clickedby = (const int*)d_in[4];
    const int*   dst_clickedby = (const int*)d_in[5];
    const int*   src_follows   = (const int*)d_in[6];
    const int*   dst_follows   = (const int*)d_in[7];
    float* out = (float*)d_out;

    const size_t user_bytes = (size_t)N_USER * DIM;           // 12.8 MB int8
    const size_t item_bytes = (size_t)N_ITEM * DIM;           // 12.8 MB int8
    const size_t need = user_bytes + item_bytes
                      + (size_t)(N_USER + N_ITEM) * sizeof(float);

    if (ws_size >= need) {
        signed char* qu = (signed char*)d_ws;
        signed char* qi = qu + user_bytes;
        float* su    = (float*)(qi + item_bytes);
        float* sitem = su + N_USER;

        // quantize both tables: 200k rows x 16 lanes
        const long long qthreads = (long long)NROWS * 16;
        quantize_rows<<<(int)((qthreads + 255) / 256), 256, 0, stream>>>(
            h_user, h_item, qu, qi, su, sitem);

        // score: 750k groups x 8 lanes
        const long long n_groups = (3LL * NEDGE) / 2;
        const long long sthreads = n_groups * 8;
        hetero_score_i8<<<(int)((sthreads + 255) / 256), 256, 0, stream>>>(
            qu, qi, su, sitem, src_clicks, dst_clicks, src_clickedby,
            dst_clickedby, src_follows, dst_follows, out);
    } else {
        const long long total_threads = 3LL * NEDGE * 32;
        hetero_score_f32<<<(int)((total_threads + 255) / 256), 256, 0, stream>>>(
            h_user, h_item, src_clicks, dst_clicks, src_clickedby, dst_clickedby,
            src_follows, dst_follows, out);
    }
}